// Round 4
// baseline (573.926 us; speedup 1.0000x reference)
//
#include <hip/hip_runtime.h>
#include <hip/hip_bf16.h>
#include <math.h>

// Problem constants
#define B_  2
#define K_  512
#define SD_ 60
#define NA_ 5
#define E_  256
#define H_  4
#define D_  64
#define FF_ 1024
#define NL_ 2
#define L_  (3 * K_)          // 1536 tokens per batch
#define M_  (B_ * L_)         // 3072 rows total
#define EPS_F 1e-6f
#define LN_EPS 1e-5f
#define CHK 64
#define NC_ (L_ / CHK)        // 24 chunks per (b,h)
#define NBLK 224              // persistent grid (<= 256 CUs, co-residency margin)

using bf16x8 = __attribute__((ext_vector_type(8))) short;
using f32x4  = __attribute__((ext_vector_type(4))) float;
typedef unsigned short u16;

__device__ inline u16 f2b(float v) {
    __hip_bfloat16 h = __float2bfloat16(v);
    return *(u16*)&h;
}
__device__ inline float b2f(u16 v) {
    __hip_bfloat16 h = *(__hip_bfloat16*)&v;
    return __bfloat162float(h);
}

struct MP {
    const float *rtg, *state, *action, *rtg_w, *rtg_b, *state_w, *state_b,
                *action_w, *action_b, *pos;
    const float *n1g, *n1b, *qkv_b, *out_b, *n2g, *n2b, *f1b, *ffn2b,
                *nfg, *nfb, *pw, *pb;
    const float *qkv_w, *out_w, *f1w, *f2w;
    float *x, *S, *Z, *out;
    u16 *yb, *qkvb, *att, *h1, *qkvT, *outT, *f1T, *f2T;
    unsigned *bar;
};

// ---------------------------------------------------------------------------
// Software grid barrier: device-scope atomics + agent fences (cross-XCD safe).
// Generation-counting, so it is reusable; counter zeroed per kernel_launch.
// ---------------------------------------------------------------------------
__device__ inline void gbar(unsigned* c) {
    __syncthreads();
    if (threadIdx.x == 0) {
        __threadfence();                       // release: L2 writeback
        unsigned t = atomicAdd(c, 1u);
        unsigned target = (t / gridDim.x + 1u) * gridDim.x;
        while (atomicAdd(c, 0u) < target) __builtin_amdgcn_s_sleep(2);
        __threadfence();                       // acquire: cache invalidate
    }
    __syncthreads();
}

// ---------------------------------------------------------------------------
// Weight convert+transpose, 32x32 tiles. task 0..1535.
// ---------------------------------------------------------------------------
__device__ void dev_transpose(int tb, const MP& p, char* sm) {
    u16 (*T)[33] = (u16(*)[33])sm;
    int layer = tb / 768;
    int r = tb % 768;
    const float* src; u16* dst; int K, N, tidx;
    if (r < 192)      { src = p.qkv_w + layer * 196608; dst = p.qkvT + layer * 196608; K = 256;  N = 768;  tidx = r; }
    else if (r < 256) { src = p.out_w + layer * 65536;  dst = p.outT + layer * 65536;  K = 256;  N = 256;  tidx = r - 192; }
    else if (r < 512) { src = p.f1w + layer * 262144;   dst = p.f1T  + layer * 262144; K = 256;  N = 1024; tidx = r - 256; }
    else              { src = p.f2w + layer * 262144;   dst = p.f2T  + layer * 262144; K = 1024; N = 256;  tidx = r - 512; }
    int tilesN = N >> 5;
    int k0 = (tidx / tilesN) << 5;
    int n0 = (tidx % tilesN) << 5;
    int c = threadIdx.x & 31, r0 = threadIdx.x >> 5;
    for (int rr = r0; rr < 32; rr += 8)
        T[rr][c] = f2b(src[(size_t)(k0 + rr) * N + n0 + c]);
    __syncthreads();
    for (int rr = r0; rr < 32; rr += 8)
        dst[(size_t)(n0 + rr) * K + k0 + c] = T[c][rr];
}

// ---------------------------------------------------------------------------
// Embed + interleave + LN1(layer0). idx 0..767, 4 tokens per task (1/wave).
// ---------------------------------------------------------------------------
__device__ void dev_embed(int idx, const MP& p) {
    int tok = idx * 4 + (threadIdx.x >> 6);
    int lane = threadIdx.x & 63;
    int b = tok / L_, l = tok % L_;
    int j = l % 3, t = l / 3;
    int e0 = lane * 4;
    float4 val = *(const float4*)(p.pos + t * E_ + e0);
    if (j == 0) {
        float rv = p.rtg[b * K_ + t];
        float4 w = *(const float4*)(p.rtg_w + e0);
        float4 bb = *(const float4*)(p.rtg_b + e0);
        val.x += rv * w.x + bb.x; val.y += rv * w.y + bb.y;
        val.z += rv * w.z + bb.z; val.w += rv * w.w + bb.w;
    } else if (j == 1) {
        float4 a = *(const float4*)(p.state_b + e0);
        const float* srow = p.state + ((size_t)b * K_ + t) * SD_;
        for (int i = 0; i < SD_; i++) {
            float s = srow[i];
            float4 w = *(const float4*)(p.state_w + (size_t)i * E_ + e0);
            a.x += s * w.x; a.y += s * w.y; a.z += s * w.z; a.w += s * w.w;
        }
        val.x += a.x; val.y += a.y; val.z += a.z; val.w += a.w;
    } else {
        float4 a = *(const float4*)(p.action_b + e0);
        const float* arow = p.action + ((size_t)b * K_ + t) * NA_;
        #pragma unroll
        for (int i = 0; i < NA_; i++) {
            float s = arow[i];
            float4 w = *(const float4*)(p.action_w + (size_t)i * E_ + e0);
            a.x += s * w.x; a.y += s * w.y; a.z += s * w.z; a.w += s * w.w;
        }
        val.x += a.x; val.y += a.y; val.z += a.z; val.w += a.w;
    }
    *(float4*)(p.x + (size_t)tok * E_ + e0) = val;
    float s = val.x + val.y + val.z + val.w;
    #pragma unroll
    for (int o = 32; o; o >>= 1) s += __shfl_xor(s, o, 64);
    float mean = s * (1.f / E_);
    float dx = val.x - mean, dy = val.y - mean, dz = val.z - mean, dw = val.w - mean;
    float q = dx * dx + dy * dy + dz * dz + dw * dw;
    #pragma unroll
    for (int o = 32; o; o >>= 1) q += __shfl_xor(q, o, 64);
    float inv = rsqrtf(q * (1.f / E_) + LN_EPS);
    float4 gv = *(const float4*)(p.n1g + e0);
    float4 bv = *(const float4*)(p.n1b + e0);
    ushort4 u;
    u.x = f2b(dx * inv * gv.x + bv.x); u.y = f2b(dy * inv * gv.y + bv.y);
    u.z = f2b(dz * inv * gv.z + bv.z); u.w = f2b(dw * inv * gv.w + bv.w);
    *(ushort4*)(p.yb + (size_t)tok * E_ + e0) = u;
}

// ---------------------------------------------------------------------------
// 128x128 MFMA GEMM (round-2 proven shape), LDS dbuf pipeline, BK=32.
// EPI: 1 exact gelu, 2 phi(relu+eps) on cols < 512
// ---------------------------------------------------------------------------
template <int EPI>
__device__ void dev_mgemm128(
    int task, int TN,
    const u16* __restrict__ A, const u16* __restrict__ Bt,
    const float* __restrict__ bias, u16* __restrict__ C,
    int N, int Kd, char* sm)
{
    u16* As = (u16*)sm;              // [2][128*40]
    u16* Bs = (u16*)(sm + 20480);    // [2][128*40]
    int tid = threadIdx.x;
    int bm = (task / TN) * 128, bn = (task % TN) * 128;
    int wave = tid >> 6, lane = tid & 63;
    int wm = (wave >> 1) * 64, wn = (wave & 1) * 64;
    int lr = lane & 15, kg = lane >> 4;

    int r0 = tid >> 2, g0 = (tid & 3) * 8;
    int r1 = r0 + 64;

    const u16* Ap0 = A + (size_t)(bm + r0) * Kd + g0;
    const u16* Ap1 = A + (size_t)(bm + r1) * Kd + g0;
    const u16* Bp0 = Bt + (size_t)(bn + r0) * Kd + g0;
    const u16* Bp1 = Bt + (size_t)(bn + r1) * Kd + g0;

    uint4 a0 = *(const uint4*)(Ap0);
    uint4 a1 = *(const uint4*)(Ap1);
    uint4 b0 = *(const uint4*)(Bp0);
    uint4 b1 = *(const uint4*)(Bp1);
    *(uint4*)&As[r0 * 40 + g0] = a0;
    *(uint4*)&As[r1 * 40 + g0] = a1;
    *(uint4*)&Bs[r0 * 40 + g0] = b0;
    *(uint4*)&Bs[r1 * 40 + g0] = b1;

    f32x4 acc[4][4] = {};
    int NT = Kd >> 5;
    for (int t = 0; t < NT; ++t) {
        int cur = t & 1;
        __syncthreads();
        if (t + 1 < NT) {
            int k1 = (t + 1) << 5;
            a0 = *(const uint4*)(Ap0 + k1);
            a1 = *(const uint4*)(Ap1 + k1);
            b0 = *(const uint4*)(Bp0 + k1);
            b1 = *(const uint4*)(Bp1 + k1);
        }
        bf16x8 af[4], bg[4];
        #pragma unroll
        for (int i = 0; i < 4; i++)
            af[i] = *(const bf16x8*)&As[cur * 5120 + (wm + i * 16 + lr) * 40 + kg * 8];
        #pragma unroll
        for (int j = 0; j < 4; j++)
            bg[j] = *(const bf16x8*)&Bs[cur * 5120 + (wn + j * 16 + lr) * 40 + kg * 8];
        #pragma unroll
        for (int i = 0; i < 4; i++)
            #pragma unroll
            for (int j = 0; j < 4; j++)
                acc[i][j] = __builtin_amdgcn_mfma_f32_16x16x32_bf16(
                    af[i], bg[j], acc[i][j], 0, 0, 0);
        if (t + 1 < NT) {
            *(uint4*)&As[(cur ^ 1) * 5120 + r0 * 40 + g0] = a0;
            *(uint4*)&As[(cur ^ 1) * 5120 + r1 * 40 + g0] = a1;
            *(uint4*)&Bs[(cur ^ 1) * 5120 + r0 * 40 + g0] = b0;
            *(uint4*)&Bs[(cur ^ 1) * 5120 + r1 * 40 + g0] = b1;
        }
    }
    __syncthreads();

    #pragma unroll
    for (int i = 0; i < 4; i++) {
        #pragma unroll
        for (int j = 0; j < 4; j++) {
            int col = bn + wn + j * 16 + lr;
            float bc = bias[col];
            #pragma unroll
            for (int r = 0; r < 4; r++) {
                int row = bm + wm + i * 16 + kg * 4 + r;
                float v = acc[i][j][r] + bc;
                if (EPI == 1) v = 0.5f * v * (1.0f + erff(v * 0.70710678118654752f));
                if (EPI == 2) { if (col < 512) v = fmaxf(v, 0.f) + EPS_F; }
                C[(size_t)row * N + col] = f2b(v);
            }
        }
    }
}

// ---------------------------------------------------------------------------
// Chunked linear attention pass A. blk 0..191.
// ---------------------------------------------------------------------------
__device__ void dev_chunk_sum(int blk, const u16* __restrict__ QKV,
                              float* __restrict__ S, float* __restrict__ Z,
                              char* sm) {
    int c = blk % NC_;
    int bh = blk / NC_;
    int h = bh % H_;
    int b = bh / H_;
    u16* Kt = (u16*)sm;             // [d][t] 64*72
    u16* Vt = (u16*)(sm + 9216);    // [e][t]
    int tid = threadIdx.x;
    const size_t base = ((size_t)b * L_ + (size_t)c * CHK) * 768 + h * 64;
    for (int i = tid; i < 1024; i += 256) {
        int t = i >> 4, d4 = (i & 15) << 2;
        ushort4 k = *(const ushort4*)(QKV + base + (size_t)t * 768 + 256 + d4);
        ushort4 v = *(const ushort4*)(QKV + base + (size_t)t * 768 + 512 + d4);
        Kt[(d4 + 0) * 72 + t] = k.x;
        Kt[(d4 + 1) * 72 + t] = k.y;
        Kt[(d4 + 2) * 72 + t] = k.z;
        Kt[(d4 + 3) * 72 + t] = k.w;
        Vt[(d4 + 0) * 72 + t] = v.x;
        Vt[(d4 + 1) * 72 + t] = v.y;
        Vt[(d4 + 2) * 72 + t] = v.z;
        Vt[(d4 + 3) * 72 + t] = v.w;
    }
    __syncthreads();
    int wave = tid >> 6, lane = tid & 63;
    int lr = lane & 15, kg = lane >> 4;
    int wm = wave * 16;
    bf16x8 a0 = *(const bf16x8*)&Kt[(wm + lr) * 72 + kg * 8];
    bf16x8 a1 = *(const bf16x8*)&Kt[(wm + lr) * 72 + 32 + kg * 8];
    f32x4 acc[4] = {};
    #pragma unroll
    for (int j = 0; j < 4; j++) {
        bf16x8 b0 = *(const bf16x8*)&Vt[(j * 16 + lr) * 72 + kg * 8];
        bf16x8 b1 = *(const bf16x8*)&Vt[(j * 16 + lr) * 72 + 32 + kg * 8];
        acc[j] = __builtin_amdgcn_mfma_f32_16x16x32_bf16(a0, b0, acc[j], 0, 0, 0);
        acc[j] = __builtin_amdgcn_mfma_f32_16x16x32_bf16(a1, b1, acc[j], 0, 0, 0);
    }
    if (tid < 64) {
        float z = 0.f;
        #pragma unroll 8
        for (int t = 0; t < 64; t++) z += b2f(Kt[tid * 72 + t]);
        Z[(size_t)blk * 64 + tid] = z;
    }
    float* Sp = S + (size_t)blk * 4096;
    #pragma unroll
    for (int j = 0; j < 4; j++) {
        #pragma unroll
        for (int rr = 0; rr < 4; rr++) {
            int d = wm + kg * 4 + rr;
            int e = j * 16 + lr;
            Sp[d * 64 + e] = acc[j][rr];
        }
    }
}

// ---------------------------------------------------------------------------
// Chunked linear attention pass B. blk 0..191.
// ---------------------------------------------------------------------------
__device__ void dev_chunk_out(int blk, const u16* __restrict__ QKV,
                              const float* __restrict__ S,
                              const float* __restrict__ Z,
                              u16* __restrict__ O, char* sm) {
    int c = blk % NC_;
    int bh = blk / NC_;
    int h = bh % H_;
    int b = bh / H_;
    u16* Qb  = (u16*)sm;              // [t][d]
    u16* Kb  = (u16*)(sm + 9216);     // [t][d]
    u16* Vt  = (u16*)(sm + 18432);    // [e][t]
    u16* KVt = (u16*)(sm + 27648);    // [e][d]
    u16* Ps  = (u16*)(sm + 36864);    // [t][s]
    float* kzs  = (float*)(sm + 46080);
    float* rows = kzs + 64;
    float* invs = rows + 64;
    int tid = threadIdx.x;
    const size_t base = ((size_t)b * L_ + (size_t)c * CHK) * 768 + h * 64;
    const float* Sbh = S + (size_t)bh * NC_ * 4096;
    for (int i = tid; i < 1024; i += 256) {
        int t = i >> 4, d4 = (i & 15) << 2;
        ushort4 q = *(const ushort4*)(QKV + base + (size_t)t * 768 + d4);
        ushort4 k = *(const ushort4*)(QKV + base + (size_t)t * 768 + 256 + d4);
        ushort4 v = *(const ushort4*)(QKV + base + (size_t)t * 768 + 512 + d4);
        *(ushort4*)&Qb[t * 72 + d4] = q;
        *(ushort4*)&Kb[t * 72 + d4] = k;
        Vt[(d4 + 0) * 72 + t] = v.x;
        Vt[(d4 + 1) * 72 + t] = v.y;
        Vt[(d4 + 2) * 72 + t] = v.z;
        Vt[(d4 + 3) * 72 + t] = v.w;
        int d = t, e4 = d4;
        float4 a = make_float4(0.f, 0.f, 0.f, 0.f);
        for (int cc = 0; cc < c; cc++) {
            float4 s4 = *(const float4*)(Sbh + (size_t)cc * 4096 + d * 64 + e4);
            a.x += s4.x; a.y += s4.y; a.z += s4.z; a.w += s4.w;
        }
        KVt[(e4 + 0) * 72 + d] = f2b(a.x);
        KVt[(e4 + 1) * 72 + d] = f2b(a.y);
        KVt[(e4 + 2) * 72 + d] = f2b(a.z);
        KVt[(e4 + 3) * 72 + d] = f2b(a.w);
    }
    if (tid < 64) {
        float z = 0.f;
        const float* Zbh = Z + (size_t)bh * NC_ * 64;
        for (int cc = 0; cc < c; cc++) z += Zbh[cc * 64 + tid];
        kzs[tid] = z;
    }
    __syncthreads();

    int wave = tid >> 6, lane = tid & 63;
    int lr = lane & 15, kg = lane >> 4;
    int wm = wave * 16;

    bf16x8 aq0 = *(const bf16x8*)&Qb[(wm + lr) * 72 + kg * 8];
    bf16x8 aq1 = *(const bf16x8*)&Qb[(wm + lr) * 72 + 32 + kg * 8];

    f32x4 accs[4] = {};
    #pragma unroll
    for (int j = 0; j < 4; j++) {
        bf16x8 b0 = *(const bf16x8*)&Kb[(j * 16 + lr) * 72 + kg * 8];
        bf16x8 b1 = *(const bf16x8*)&Kb[(j * 16 + lr) * 72 + 32 + kg * 8];
        accs[j] = __builtin_amdgcn_mfma_f32_16x16x32_bf16(aq0, b0, accs[j], 0, 0, 0);
        accs[j] = __builtin_amdgcn_mfma_f32_16x16x32_bf16(aq1, b1, accs[j], 0, 0, 0);
    }
    float rsum[4] = {0.f, 0.f, 0.f, 0.f};
    #pragma unroll
    for (int j = 0; j < 4; j++) {
        #pragma unroll
        for (int rr = 0; rr < 4; rr++) {
            int m = wm + kg * 4 + rr;
            int n = j * 16 + lr;
            float v = (n <= m) ? accs[j][rr] : 0.f;
            rsum[rr] += v;
            Ps[m * 72 + n] = f2b(v);
        }
    }
    #pragma unroll
    for (int rr = 0; rr < 4; rr++) {
        float s = rsum[rr];
        s += __shfl_xor(s, 1, 64);
        s += __shfl_xor(s, 2, 64);
        s += __shfl_xor(s, 4, 64);
        s += __shfl_xor(s, 8, 64);
        if (lr == 0) rows[wm + kg * 4 + rr] = s;
    }
    __syncthreads();

    if (tid < 64) {
        float den = rows[tid];
        float acc = 0.f;
        #pragma unroll 8
        for (int d = 0; d < 64; d++) acc += b2f(Qb[tid * 72 + d]) * kzs[d];
        invs[tid] = 1.f / fmaxf(den + acc, 1e-6f);
    }

    bf16x8 ap0 = *(const bf16x8*)&Ps[(wm + lr) * 72 + kg * 8];
    bf16x8 ap1 = *(const bf16x8*)&Ps[(wm + lr) * 72 + 32 + kg * 8];
    f32x4 accn[4] = {};
    #pragma unroll
    for (int j = 0; j < 4; j++) {
        bf16x8 b0 = *(const bf16x8*)&KVt[(j * 16 + lr) * 72 + kg * 8];
        bf16x8 b1 = *(const bf16x8*)&KVt[(j * 16 + lr) * 72 + 32 + kg * 8];
        accn[j] = __builtin_amdgcn_mfma_f32_16x16x32_bf16(aq0, b0, accn[j], 0, 0, 0);
        accn[j] = __builtin_amdgcn_mfma_f32_16x16x32_bf16(aq1, b1, accn[j], 0, 0, 0);
        bf16x8 c0 = *(const bf16x8*)&Vt[(j * 16 + lr) * 72 + kg * 8];
        bf16x8 c1 = *(const bf16x8*)&Vt[(j * 16 + lr) * 72 + 32 + kg * 8];
        accn[j] = __builtin_amdgcn_mfma_f32_16x16x32_bf16(ap0, c0, accn[j], 0, 0, 0);
        accn[j] = __builtin_amdgcn_mfma_f32_16x16x32_bf16(ap1, c1, accn[j], 0, 0, 0);
    }
    __syncthreads();

    u16* Op = O + ((size_t)b * L_ + (size_t)c * CHK) * E_ + h * 64;
    #pragma unroll
    for (int j = 0; j < 4; j++) {
        #pragma unroll
        for (int rr = 0; rr < 4; rr++) {
            int m = wm + kg * 4 + rr;
            int e = j * 16 + lr;
            Op[(size_t)m * E_ + e] = f2b(accn[j][rr] * invs[m]);
        }
    }
}

// ---------------------------------------------------------------------------
// 32x256 tile: X += A@Bt^T + bias (residual, fp32), then per-row epilogue.
// 256 threads, 4 waves (each 32 rows x 64 cols). BK=32, LDS dbuf pipeline.
// MODE 1: LayerNorm(row) -> Y bf16. MODE 2: final LN + pred head -> Out.
// ---------------------------------------------------------------------------
template <int MODE>
__device__ void dev_gres32(
    int task, const u16* __restrict__ A, const u16* __restrict__ Bt,
    const float* __restrict__ bias, float* __restrict__ X,
    const float* __restrict__ g, const float* __restrict__ bt,
    u16* __restrict__ Y, const float* __restrict__ W,
    const float* __restrict__ pb, float* __restrict__ Out,
    int Kd, char* sm)
{
    u16* AsB = (u16*)sm;             // [2][32*40]
    u16* BsB = (u16*)(sm + 5120);    // [2][256*40]
    int tid = threadIdx.x;
    int bm = task * 32;
    int wave = tid >> 6, lane = tid & 63;
    int wn = wave * 64;
    int lr = lane & 15, kg = lane >> 4;

    int sr = tid >> 2, ag = (tid & 3) * 8;   // sr: 0..63
    bool al = sr < 32;

    const u16* Ap = A + (size_t)(bm + sr) * Kd + ag;     // valid iff al
    const u16* Bp = Bt + (size_t)sr * Kd + ag;           // +64*q rows

    uint4 aR, bR[4];
    if (al) aR = *(const uint4*)(Ap);
    #pragma unroll
    for (int q = 0; q < 4; q++) bR[q] = *(const uint4*)(Bp + (size_t)(64 * q) * Kd);
    if (al) *(uint4*)&AsB[sr * 40 + ag] = aR;
    #pragma unroll
    for (int q = 0; q < 4; q++) *(uint4*)&BsB[(sr + 64 * q) * 40 + ag] = bR[q];

    f32x4 acc[2][4] = {};
    int NT = Kd >> 5;
    for (int t = 0; t < NT; ++t) {
        int cur = t & 1;
        __syncthreads();
        if (t + 1 < NT) {
            int k1 = (t + 1) << 5;
            if (al) aR = *(const uint4*)(Ap + k1);
            #pragma unroll
            for (int q = 0; q < 4; q++)
                bR[q] = *(const uint4*)(Bp + (size_t)(64 * q) * Kd + k1);
        }
        bf16x8 af[2], bg[4];
        #pragma unroll
        for (int i = 0; i < 2; i++)
            af[i] = *(const bf16x8*)&AsB[cur * 1280 + (i * 16 + lr) * 40 + kg * 8];
        #pragma unroll
        for (int j = 0; j < 4; j++)
            bg[j] = *(const bf16x8*)&BsB[cur * 10240 + (wn + j * 16 + lr) * 40 + kg * 8];
        #pragma unroll
        for (int i = 0; i < 2; i++)
            #pragma unroll
            for (int j = 0; j < 4; j++)
                acc[i][j] = __builtin_amdgcn_mfma_f32_16x16x32_bf16(
                    af[i], bg[j], acc[i][j], 0, 0, 0);
        if (t + 1 < NT) {
            if (al) *(uint4*)&AsB[(cur ^ 1) * 1280 + sr * 40 + ag] = aR;
            #pragma unroll
            for (int q = 0; q < 4; q++)
                *(uint4*)&BsB[(cur ^ 1) * 10240 + (sr + 64 * q) * 40 + ag] = bR[q];
        }
    }
    __syncthreads();   // LDS reads done; reuse as fp32 row buffer

    float* Xs = (float*)sm;    // [32][260]
    #pragma unroll
    for (int i = 0; i < 2; i++) {
        #pragma unroll
        for (int j = 0; j < 4; j++) {
            int col = wn + j * 16 + lr;
            float bc = bias[col];
            #pragma unroll
            for (int rr = 0; rr < 4; rr++) {
                int row = i * 16 + kg * 4 + rr;
                float v = acc[i][j][rr] + bc + X[(size_t)(bm + row) * 256 + col];
                Xs[row * 260 + col] = v;
            }
        }
    }
    __syncthreads();

    int e0 = lane * 4;
    #pragma unroll
    for (int rq = 0; rq < 8; rq++) {
        int row = wave * 8 + rq;
        float4 v = *(const float4*)&Xs[row * 260 + e0];
        if (MODE == 1) {
            *(float4*)(X + (size_t)(bm + row) * 256 + e0) = v;
            float s = v.x + v.y + v.z + v.w;
            #pragma unroll
            for (int o = 32; o; o >>= 1) s += __shfl_xor(s, o, 64);
            float mean = s * (1.f / E_);
            float dx = v.x - mean, dy = v.y - mean, dz = v.z - mean, dw = v.w - mean;
            float q = dx * dx + dy * dy + dz * dz + dw * dw;
            #pragma unroll
            for (int o = 32; o; o >>= 1) q += __shfl_xor(q, o, 64);
            float inv = rsqrtf(q * (1.f / E_) + LN_EPS);
            float4 gv = *(const float4*)(g + e0);
            float4 bv = *(const float4*)(bt + e0);
            ushort4 u;
            u.x = f2b(dx * inv * gv.x + bv.x); u.y = f2b(dy * inv * gv.y + bv.y);
            u.z = f2b(dz * inv * gv.z + bv.z); u.w = f2b(dw * inv * gv.w + bv.w);
            *(ushort4*)(Y + (size_t)(bm + row) * 256 + e0) = u;
        } else {
            // final layer: LN(normf) + prediction head for state tokens only
            int gr = bm + row;
            int b = gr / L_, l = gr % L_;
            if (l % 3 == 1) {
                float s = v.x + v.y + v.z + v.w;
                #pragma unroll
                for (int o = 32; o; o >>= 1) s += __shfl_xor(s, o, 64);
                float mean = s * (1.f / E_);
                float dx = v.x - mean, dy = v.y - mean, dz = v.z - mean, dw = v.w - mean;
                float q = dx * dx + dy * dy + dz * dz + dw * dw;
                #pragma unroll
                for (int o = 32; o; o >>= 1) q += __shfl_xor(q, o, 64);
                float inv = rsqrtf(q * (1.f / E_) + LN_EPS);
                float4 gv = *(const float4*)(g + e0);
                float4 bv = *(const float4*)(bt + e0);
                float y0 = dx * inv * gv.x + bv.x;
                float y1 = dy * inv * gv.y + bv.y;
                float y2 = dz * inv * gv.z + bv.z;
                float y3 = dw * inv * gv.w + bv.w;
                int si = b * K_ + l / 3;
                #pragma unroll
                for (int na = 0; na < NA_; na++) {
                    float a = y0 * W[(e0 + 0) * NA_ + na] + y1 * W[(e0 + 1) * NA_ + na]
                            + y2 * W[(e0 + 2) * NA_ + na] + y3 * W[(e0 + 3) * NA_ + na];
                    #pragma unroll
                    for (int o = 32; o; o >>= 1) a += __shfl_xor(a, o, 64);
                    if (lane == 0) Out[(size_t)si * NA_ + na] = a + pb[na];
                }
            }
        }
    }
}

// ---------------------------------------------------------------------------
// Persistent megakernel: entire forward pass, software grid barriers.
// ---------------------------------------------------------------------------
__global__ __launch_bounds__(256) void mega(MP p) {
    __shared__ __align__(16) char sm[46848];
    int NB = gridDim.x;

    // Stage 0: weight transpose (1536 tasks) + embed/LN1 (768 tasks)
    for (int t = blockIdx.x; t < 2304; t += NB) {
        if (t < 1536) dev_transpose(t, p, sm);
        else dev_embed(t - 1536, p);
        __syncthreads();
    }
    gbar(p.bar);

    for (int i = 0; i < NL_; i++) {
        // QKV projection + fused phi on q,k
        for (int t = blockIdx.x; t < 144; t += NB) {
            dev_mgemm128<2>(t, 6, p.yb, p.qkvT + (size_t)i * 196608,
                            p.qkv_b + i * 768, p.qkvb, 768, 256, sm);
            __syncthreads();
        }
        gbar(p.bar);
        for (int t = blockIdx.x; t < 192; t += NB) {
            dev_chunk_sum(t, p.qkvb, p.S, p.Z, sm);
            __syncthreads();
        }
        gbar(p.bar);
        for (int t = blockIdx.x; t < 192; t += NB) {
            dev_chunk_out(t, p.qkvb, p.S, p.Z, p.att, sm);
            __syncthreads();
        }
        gbar(p.bar);
        // attn out-proj + residual + LN2
        for (int t = blockIdx.x; t < 96; t += NB) {
            dev_gres32<1>(t, p.att, p.outT + (size_t)i * 65536, p.out_b + i * E_,
                          p.x, p.n2g + i * E_, p.n2b + i * E_, p.yb,
                          nullptr, nullptr, nullptr, 256, sm);
            __syncthreads();
        }
        gbar(p.bar);
        // FFN1 + exact gelu
        for (int t = blockIdx.x; t < 192; t += NB) {
            dev_mgemm128<1>(t, 8, p.yb, p.f1T + (size_t)i * 262144,
                            p.f1b + i * FF_, p.h1, 1024, 256, sm);
            __syncthreads();
        }
        gbar(p.bar);
        // FFN2 + residual, then LN1(next layer) or final LN + pred head
        if (i == 0) {
            for (int t = blockIdx.x; t < 96; t += NB) {
                dev_gres32<1>(t, p.h1, p.f2T, p.ffn2b, p.x,
                              p.n1g + E_, p.n1b + E_, p.yb,
                              nullptr, nullptr, nullptr, 1024, sm);
                __syncthreads();
            }
            gbar(p.bar);
        } else {
            for (int t = blockIdx.x; t < 96; t += NB) {
                dev_gres32<2>(t, p.h1, p.f2T + (size_t)i * 262144, p.ffn2b + i * E_,
                              p.x, p.nfg, p.nfb, nullptr,
                              p.pw, p.pb, p.out, 1024, sm);
                __syncthreads();
            }
        }
    }
}

// ---------------------------------------------------------------------------
extern "C" void kernel_launch(void* const* d_in, const int* in_sizes, int n_in,
                              void* d_out, int out_size, void* d_ws, size_t ws_size,
                              hipStream_t stream) {
    // workspace layout
    float* ws = (float*)d_ws;
    float* x    = ws;                        // 786432 f
    float* S    = x + 786432;                // 786432 f
    float* Z    = S + 786432;                // 12288 f
    u16*   yb   = (u16*)(Z + 12288);         // 786432 u16
    u16*   qkvb = yb + 786432;               // 2359296 u16
    u16*   att  = qkvb + 2359296;            // 786432
    u16*   h1   = att + 786432;              // 3145728
    u16*   qkvT = h1 + 3145728;              // 393216
    u16*   outT = qkvT + 393216;             // 131072
    u16*   f1T  = outT + 131072;             // 524288
    u16*   f2T  = f1T + 524288;              // 524288
    unsigned* bar = (unsigned*)(f2T + 524288);

    hipMemsetAsync(bar, 0, 64, stream);

    MP p;
    p.rtg      = (const float*)d_in[0];
    p.state    = (const float*)d_in[1];
    p.action   = (const float*)d_in[2];
    p.rtg_w    = (const float*)d_in[3];
    p.rtg_b    = (const float*)d_in[4];
    p.state_w  = (const float*)d_in[5];
    p.state_b  = (const float*)d_in[6];
    p.action_w = (const float*)d_in[7];
    p.action_b = (const float*)d_in[8];
    p.pos      = (const float*)d_in[9];
    p.n1g      = (const float*)d_in[10];
    p.n1b      = (const float*)d_in[11];
    p.qkv_w    = (const float*)d_in[12];
    p.qkv_b    = (const float*)d_in[13];
    p.out_w    = (const float*)d_in[14];
    p.out_b    = (const float*)d_in[15];
    p.n2g      = (const float*)d_in[16];
    p.n2b      = (const float*)d_in[17];
    p.f1w      = (const float*)d_in[18];
    p.f1b      = (const float*)d_in[19];
    p.f2w      = (const float*)d_in[20];
    p.ffn2b    = (const float*)d_in[21];
    p.nfg      = (const float*)d_in[22];
    p.nfb      = (const float*)d_in[23];
    p.pw       = (const float*)d_in[24];
    p.pb       = (const float*)d_in[25];
    p.x = x; p.S = S; p.Z = Z; p.out = (float*)d_out;
    p.yb = yb; p.qkvb = qkvb; p.att = att; p.h1 = h1;
    p.qkvT = qkvT; p.outT = outT; p.f1T = f1T; p.f2T = f2T;
    p.bar = bar;

    mega<<<dim3(NBLK), dim3(256), 0, stream>>>(p);
}

// Round 5
// 492.677 us; speedup vs baseline: 1.1649x; 1.1649x over previous
//
#include <hip/hip_runtime.h>
#include <hip/hip_bf16.h>
#include <math.h>

// Problem constants
#define B_  2
#define K_  512
#define SD_ 60
#define NA_ 5
#define E_  256
#define H_  4
#define D_  64
#define FF_ 1024
#define NL_ 2
#define L_  (3 * K_)          // 1536 tokens per batch
#define M_  (B_ * L_)         // 3072 rows total
#define EPS_F 1e-6f
#define LN_EPS 1e-5f
#define CHK 64
#define NC_ (L_ / CHK)        // 24 chunks per (b,h)
#define NBLK 192              // persistent grid (<= 256 CUs; 2304 stage0 tasks = 12/block)

using bf16x8 = __attribute__((ext_vector_type(8))) short;
using f32x4  = __attribute__((ext_vector_type(4))) float;
typedef unsigned short u16;

__device__ inline u16 f2b(float v) {
    __hip_bfloat16 h = __float2bfloat16(v);
    return *(u16*)&h;
}
__device__ inline float b2f(u16 v) {
    __hip_bfloat16 h = *(__hip_bfloat16*)&v;
    return __bfloat162float(h);
}

struct MP {
    const float *rtg, *state, *action, *rtg_w, *rtg_b, *state_w, *state_b,
                *action_w, *action_b, *pos;
    const float *n1g, *n1b, *qkv_b, *out_b, *n2g, *n2b, *f1b, *ffn2b,
                *nfg, *nfb, *pw, *pb;
    const float *qkv_w, *out_w, *f1w, *f2w;
    float *x, *S, *Z, *out;
    u16 *yb, *qkvb, *att, *h1, *qkvT, *outT, *f1T, *f2T;
    unsigned *bar;            // [0]=count, [32]=generation (separate lines)
};

// ---------------------------------------------------------------------------
// Sense-reversing grid barrier. Arrival: ONE fetch_add per block (pipelines).
// Poll: relaxed agent-scope atomic LOAD (no RMW -> no serialization).
// Release: last arriver resets count, then release-stores gen+1.
// __threadfence() = agent fence (L2 wb + inv) for cross-XCD data visibility.
// ---------------------------------------------------------------------------
__device__ inline void gbar(unsigned* bar) {
    __syncthreads();
    if (threadIdx.x == 0) {
        unsigned* cnt = bar;
        unsigned* gen = bar + 32;
        __threadfence();   // release: make this block's writes visible
        unsigned g = __hip_atomic_load(gen, __ATOMIC_RELAXED, __HIP_MEMORY_SCOPE_AGENT);
        unsigned a = __hip_atomic_fetch_add(cnt, 1u, __ATOMIC_ACQ_REL, __HIP_MEMORY_SCOPE_AGENT);
        if (a == (unsigned)gridDim.x - 1u) {
            __hip_atomic_store(cnt, 0u, __ATOMIC_RELAXED, __HIP_MEMORY_SCOPE_AGENT);
            __hip_atomic_store(gen, g + 1u, __ATOMIC_RELEASE, __HIP_MEMORY_SCOPE_AGENT);
        } else {
            while (__hip_atomic_load(gen, __ATOMIC_RELAXED, __HIP_MEMORY_SCOPE_AGENT) == g)
                __builtin_amdgcn_s_sleep(8);
        }
        __threadfence();   // acquire: invalidate stale cached lines
    }
    __syncthreads();
}

// ---------------------------------------------------------------------------
// Weight convert+transpose, 32x32 tiles. task 0..1535.
// ---------------------------------------------------------------------------
__device__ void dev_transpose(int tb, const MP& p, char* sm) {
    u16 (*T)[33] = (u16(*)[33])sm;
    int layer = tb / 768;
    int r = tb % 768;
    const float* src; u16* dst; int K, N, tidx;
    if (r < 192)      { src = p.qkv_w + layer * 196608; dst = p.qkvT + layer * 196608; K = 256;  N = 768;  tidx = r; }
    else if (r < 256) { src = p.out_w + layer * 65536;  dst = p.outT + layer * 65536;  K = 256;  N = 256;  tidx = r - 192; }
    else if (r < 512) { src = p.f1w + layer * 262144;   dst = p.f1T  + layer * 262144; K = 256;  N = 1024; tidx = r - 256; }
    else              { src = p.f2w + layer * 262144;   dst = p.f2T  + layer * 262144; K = 1024; N = 256;  tidx = r - 512; }
    int tilesN = N >> 5;
    int k0 = (tidx / tilesN) << 5;
    int n0 = (tidx % tilesN) << 5;
    int c = threadIdx.x & 31, r0 = threadIdx.x >> 5;
    for (int rr = r0; rr < 32; rr += 8)
        T[rr][c] = f2b(src[(size_t)(k0 + rr) * N + n0 + c]);
    __syncthreads();
    for (int rr = r0; rr < 32; rr += 8)
        dst[(size_t)(n0 + rr) * K + k0 + c] = T[c][rr];
}

// ---------------------------------------------------------------------------
// Embed + interleave + LN1(layer0). idx 0..767, 4 tokens per task (1/wave).
// ---------------------------------------------------------------------------
__device__ void dev_embed(int idx, const MP& p) {
    int tok = idx * 4 + (threadIdx.x >> 6);
    int lane = threadIdx.x & 63;
    int b = tok / L_, l = tok % L_;
    int j = l % 3, t = l / 3;
    int e0 = lane * 4;
    float4 val = *(const float4*)(p.pos + t * E_ + e0);
    if (j == 0) {
        float rv = p.rtg[b * K_ + t];
        float4 w = *(const float4*)(p.rtg_w + e0);
        float4 bb = *(const float4*)(p.rtg_b + e0);
        val.x += rv * w.x + bb.x; val.y += rv * w.y + bb.y;
        val.z += rv * w.z + bb.z; val.w += rv * w.w + bb.w;
    } else if (j == 1) {
        float4 a = *(const float4*)(p.state_b + e0);
        const float* srow = p.state + ((size_t)b * K_ + t) * SD_;
        for (int i = 0; i < SD_; i++) {
            float s = srow[i];
            float4 w = *(const float4*)(p.state_w + (size_t)i * E_ + e0);
            a.x += s * w.x; a.y += s * w.y; a.z += s * w.z; a.w += s * w.w;
        }
        val.x += a.x; val.y += a.y; val.z += a.z; val.w += a.w;
    } else {
        float4 a = *(const float4*)(p.action_b + e0);
        const float* arow = p.action + ((size_t)b * K_ + t) * NA_;
        #pragma unroll
        for (int i = 0; i < NA_; i++) {
            float s = arow[i];
            float4 w = *(const float4*)(p.action_w + (size_t)i * E_ + e0);
            a.x += s * w.x; a.y += s * w.y; a.z += s * w.z; a.w += s * w.w;
        }
        val.x += a.x; val.y += a.y; val.z += a.z; val.w += a.w;
    }
    *(float4*)(p.x + (size_t)tok * E_ + e0) = val;
    float s = val.x + val.y + val.z + val.w;
    #pragma unroll
    for (int o = 32; o; o >>= 1) s += __shfl_xor(s, o, 64);
    float mean = s * (1.f / E_);
    float dx = val.x - mean, dy = val.y - mean, dz = val.z - mean, dw = val.w - mean;
    float q = dx * dx + dy * dy + dz * dz + dw * dw;
    #pragma unroll
    for (int o = 32; o; o >>= 1) q += __shfl_xor(q, o, 64);
    float inv = rsqrtf(q * (1.f / E_) + LN_EPS);
    float4 gv = *(const float4*)(p.n1g + e0);
    float4 bv = *(const float4*)(p.n1b + e0);
    ushort4 u;
    u.x = f2b(dx * inv * gv.x + bv.x); u.y = f2b(dy * inv * gv.y + bv.y);
    u.z = f2b(dz * inv * gv.z + bv.z); u.w = f2b(dw * inv * gv.w + bv.w);
    *(ushort4*)(p.yb + (size_t)tok * E_ + e0) = u;
}

// ---------------------------------------------------------------------------
// 128x128 MFMA GEMM, LDS dbuf pipeline, BK=32.
// EPI: 1 exact gelu, 2 phi(relu+eps) on cols < 512
// ---------------------------------------------------------------------------
template <int EPI>
__device__ void dev_mgemm128(
    int task, int TN,
    const u16* __restrict__ A, const u16* __restrict__ Bt,
    const float* __restrict__ bias, u16* __restrict__ C,
    int N, int Kd, char* sm)
{
    u16* As = (u16*)sm;              // [2][128*40]
    u16* Bs = (u16*)(sm + 20480);    // [2][128*40]
    int tid = threadIdx.x;
    int bm = (task / TN) * 128, bn = (task % TN) * 128;
    int wave = tid >> 6, lane = tid & 63;
    int wm = (wave >> 1) * 64, wn = (wave & 1) * 64;
    int lr = lane & 15, kg = lane >> 4;

    int r0 = tid >> 2, g0 = (tid & 3) * 8;
    int r1 = r0 + 64;

    const u16* Ap0 = A + (size_t)(bm + r0) * Kd + g0;
    const u16* Ap1 = A + (size_t)(bm + r1) * Kd + g0;
    const u16* Bp0 = Bt + (size_t)(bn + r0) * Kd + g0;
    const u16* Bp1 = Bt + (size_t)(bn + r1) * Kd + g0;

    uint4 a0 = *(const uint4*)(Ap0);
    uint4 a1 = *(const uint4*)(Ap1);
    uint4 b0 = *(const uint4*)(Bp0);
    uint4 b1 = *(const uint4*)(Bp1);
    *(uint4*)&As[r0 * 40 + g0] = a0;
    *(uint4*)&As[r1 * 40 + g0] = a1;
    *(uint4*)&Bs[r0 * 40 + g0] = b0;
    *(uint4*)&Bs[r1 * 40 + g0] = b1;

    f32x4 acc[4][4] = {};
    int NT = Kd >> 5;
    for (int t = 0; t < NT; ++t) {
        int cur = t & 1;
        __syncthreads();
        if (t + 1 < NT) {
            int k1 = (t + 1) << 5;
            a0 = *(const uint4*)(Ap0 + k1);
            a1 = *(const uint4*)(Ap1 + k1);
            b0 = *(const uint4*)(Bp0 + k1);
            b1 = *(const uint4*)(Bp1 + k1);
        }
        bf16x8 af[4], bg[4];
        #pragma unroll
        for (int i = 0; i < 4; i++)
            af[i] = *(const bf16x8*)&As[cur * 5120 + (wm + i * 16 + lr) * 40 + kg * 8];
        #pragma unroll
        for (int j = 0; j < 4; j++)
            bg[j] = *(const bf16x8*)&Bs[cur * 5120 + (wn + j * 16 + lr) * 40 + kg * 8];
        #pragma unroll
        for (int i = 0; i < 4; i++)
            #pragma unroll
            for (int j = 0; j < 4; j++)
                acc[i][j] = __builtin_amdgcn_mfma_f32_16x16x32_bf16(
                    af[i], bg[j], acc[i][j], 0, 0, 0);
        if (t + 1 < NT) {
            *(uint4*)&As[(cur ^ 1) * 5120 + r0 * 40 + g0] = a0;
            *(uint4*)&As[(cur ^ 1) * 5120 + r1 * 40 + g0] = a1;
            *(uint4*)&Bs[(cur ^ 1) * 5120 + r0 * 40 + g0] = b0;
            *(uint4*)&Bs[(cur ^ 1) * 5120 + r1 * 40 + g0] = b1;
        }
    }
    __syncthreads();

    #pragma unroll
    for (int i = 0; i < 4; i++) {
        #pragma unroll
        for (int j = 0; j < 4; j++) {
            int col = bn + wn + j * 16 + lr;
            float bc = bias[col];
            #pragma unroll
            for (int r = 0; r < 4; r++) {
                int row = bm + wm + i * 16 + kg * 4 + r;
                float v = acc[i][j][r] + bc;
                if (EPI == 1) v = 0.5f * v * (1.0f + erff(v * 0.70710678118654752f));
                if (EPI == 2) { if (col < 512) v = fmaxf(v, 0.f) + EPS_F; }
                C[(size_t)row * N + col] = f2b(v);
            }
        }
    }
}

// ---------------------------------------------------------------------------
// Chunked linear attention pass A. blk 0..191.
// ---------------------------------------------------------------------------
__device__ void dev_chunk_sum(int blk, const u16* __restrict__ QKV,
                              float* __restrict__ S, float* __restrict__ Z,
                              char* sm) {
    int c = blk % NC_;
    int bh = blk / NC_;
    int h = bh % H_;
    int b = bh / H_;
    u16* Kt = (u16*)sm;             // [d][t] 64*72
    u16* Vt = (u16*)(sm + 9216);    // [e][t]
    int tid = threadIdx.x;
    const size_t base = ((size_t)b * L_ + (size_t)c * CHK) * 768 + h * 64;
    for (int i = tid; i < 1024; i += 256) {
        int t = i >> 4, d4 = (i & 15) << 2;
        ushort4 k = *(const ushort4*)(QKV + base + (size_t)t * 768 + 256 + d4);
        ushort4 v = *(const ushort4*)(QKV + base + (size_t)t * 768 + 512 + d4);
        Kt[(d4 + 0) * 72 + t] = k.x;
        Kt[(d4 + 1) * 72 + t] = k.y;
        Kt[(d4 + 2) * 72 + t] = k.z;
        Kt[(d4 + 3) * 72 + t] = k.w;
        Vt[(d4 + 0) * 72 + t] = v.x;
        Vt[(d4 + 1) * 72 + t] = v.y;
        Vt[(d4 + 2) * 72 + t] = v.z;
        Vt[(d4 + 3) * 72 + t] = v.w;
    }
    __syncthreads();
    int wave = tid >> 6, lane = tid & 63;
    int lr = lane & 15, kg = lane >> 4;
    int wm = wave * 16;
    bf16x8 a0 = *(const bf16x8*)&Kt[(wm + lr) * 72 + kg * 8];
    bf16x8 a1 = *(const bf16x8*)&Kt[(wm + lr) * 72 + 32 + kg * 8];
    f32x4 acc[4] = {};
    #pragma unroll
    for (int j = 0; j < 4; j++) {
        bf16x8 b0 = *(const bf16x8*)&Vt[(j * 16 + lr) * 72 + kg * 8];
        bf16x8 b1 = *(const bf16x8*)&Vt[(j * 16 + lr) * 72 + 32 + kg * 8];
        acc[j] = __builtin_amdgcn_mfma_f32_16x16x32_bf16(a0, b0, acc[j], 0, 0, 0);
        acc[j] = __builtin_amdgcn_mfma_f32_16x16x32_bf16(a1, b1, acc[j], 0, 0, 0);
    }
    if (tid < 64) {
        float z = 0.f;
        #pragma unroll 8
        for (int t = 0; t < 64; t++) z += b2f(Kt[tid * 72 + t]);
        Z[(size_t)blk * 64 + tid] = z;
    }
    float* Sp = S + (size_t)blk * 4096;
    #pragma unroll
    for (int j = 0; j < 4; j++) {
        #pragma unroll
        for (int rr = 0; rr < 4; rr++) {
            int d = wm + kg * 4 + rr;
            int e = j * 16 + lr;
            Sp[d * 64 + e] = acc[j][rr];
        }
    }
}

// ---------------------------------------------------------------------------
// Chunked linear attention pass B. blk 0..191.
// ---------------------------------------------------------------------------
__device__ void dev_chunk_out(int blk, const u16* __restrict__ QKV,
                              const float* __restrict__ S,
                              const float* __restrict__ Z,
                              u16* __restrict__ O, char* sm) {
    int c = blk % NC_;
    int bh = blk / NC_;
    int h = bh % H_;
    int b = bh / H_;
    u16* Qb  = (u16*)sm;              // [t][d]
    u16* Kb  = (u16*)(sm + 9216);     // [t][d]
    u16* Vt  = (u16*)(sm + 18432);    // [e][t]
    u16* KVt = (u16*)(sm + 27648);    // [e][d]
    u16* Ps  = (u16*)(sm + 36864);    // [t][s]
    float* kzs  = (float*)(sm + 46080);
    float* rows = kzs + 64;
    float* invs = rows + 64;
    int tid = threadIdx.x;
    const size_t base = ((size_t)b * L_ + (size_t)c * CHK) * 768 + h * 64;
    const float* Sbh = S + (size_t)bh * NC_ * 4096;
    for (int i = tid; i < 1024; i += 256) {
        int t = i >> 4, d4 = (i & 15) << 2;
        ushort4 q = *(const ushort4*)(QKV + base + (size_t)t * 768 + d4);
        ushort4 k = *(const ushort4*)(QKV + base + (size_t)t * 768 + 256 + d4);
        ushort4 v = *(const ushort4*)(QKV + base + (size_t)t * 768 + 512 + d4);
        *(ushort4*)&Qb[t * 72 + d4] = q;
        *(ushort4*)&Kb[t * 72 + d4] = k;
        Vt[(d4 + 0) * 72 + t] = v.x;
        Vt[(d4 + 1) * 72 + t] = v.y;
        Vt[(d4 + 2) * 72 + t] = v.z;
        Vt[(d4 + 3) * 72 + t] = v.w;
        int d = t, e4 = d4;
        float4 a = make_float4(0.f, 0.f, 0.f, 0.f);
        for (int cc = 0; cc < c; cc++) {
            float4 s4 = *(const float4*)(Sbh + (size_t)cc * 4096 + d * 64 + e4);
            a.x += s4.x; a.y += s4.y; a.z += s4.z; a.w += s4.w;
        }
        KVt[(e4 + 0) * 72 + d] = f2b(a.x);
        KVt[(e4 + 1) * 72 + d] = f2b(a.y);
        KVt[(e4 + 2) * 72 + d] = f2b(a.z);
        KVt[(e4 + 3) * 72 + d] = f2b(a.w);
    }
    if (tid < 64) {
        float z = 0.f;
        const float* Zbh = Z + (size_t)bh * NC_ * 64;
        for (int cc = 0; cc < c; cc++) z += Zbh[cc * 64 + tid];
        kzs[tid] = z;
    }
    __syncthreads();

    int wave = tid >> 6, lane = tid & 63;
    int lr = lane & 15, kg = lane >> 4;
    int wm = wave * 16;

    bf16x8 aq0 = *(const bf16x8*)&Qb[(wm + lr) * 72 + kg * 8];
    bf16x8 aq1 = *(const bf16x8*)&Qb[(wm + lr) * 72 + 32 + kg * 8];

    f32x4 accs[4] = {};
    #pragma unroll
    for (int j = 0; j < 4; j++) {
        bf16x8 b0 = *(const bf16x8*)&Kb[(j * 16 + lr) * 72 + kg * 8];
        bf16x8 b1 = *(const bf16x8*)&Kb[(j * 16 + lr) * 72 + 32 + kg * 8];
        accs[j] = __builtin_amdgcn_mfma_f32_16x16x32_bf16(aq0, b0, accs[j], 0, 0, 0);
        accs[j] = __builtin_amdgcn_mfma_f32_16x16x32_bf16(aq1, b1, accs[j], 0, 0, 0);
    }
    float rsum[4] = {0.f, 0.f, 0.f, 0.f};
    #pragma unroll
    for (int j = 0; j < 4; j++) {
        #pragma unroll
        for (int rr = 0; rr < 4; rr++) {
            int m = wm + kg * 4 + rr;
            int n = j * 16 + lr;
            float v = (n <= m) ? accs[j][rr] : 0.f;
            rsum[rr] += v;
            Ps[m * 72 + n] = f2b(v);
        }
    }
    #pragma unroll
    for (int rr = 0; rr < 4; rr++) {
        float s = rsum[rr];
        s += __shfl_xor(s, 1, 64);
        s += __shfl_xor(s, 2, 64);
        s += __shfl_xor(s, 4, 64);
        s += __shfl_xor(s, 8, 64);
        if (lr == 0) rows[wm + kg * 4 + rr] = s;
    }
    __syncthreads();

    if (tid < 64) {
        float den = rows[tid];
        float acc = 0.f;
        #pragma unroll 8
        for (int d = 0; d < 64; d++) acc += b2f(Qb[tid * 72 + d]) * kzs[d];
        invs[tid] = 1.f / fmaxf(den + acc, 1e-6f);
    }

    bf16x8 ap0 = *(const bf16x8*)&Ps[(wm + lr) * 72 + kg * 8];
    bf16x8 ap1 = *(const bf16x8*)&Ps[(wm + lr) * 72 + 32 + kg * 8];
    f32x4 accn[4] = {};
    #pragma unroll
    for (int j = 0; j < 4; j++) {
        bf16x8 b0 = *(const bf16x8*)&KVt[(j * 16 + lr) * 72 + kg * 8];
        bf16x8 b1 = *(const bf16x8*)&KVt[(j * 16 + lr) * 72 + 32 + kg * 8];
        accn[j] = __builtin_amdgcn_mfma_f32_16x16x32_bf16(aq0, b0, accn[j], 0, 0, 0);
        accn[j] = __builtin_amdgcn_mfma_f32_16x16x32_bf16(aq1, b1, accn[j], 0, 0, 0);
        bf16x8 c0 = *(const bf16x8*)&Vt[(j * 16 + lr) * 72 + kg * 8];
        bf16x8 c1 = *(const bf16x8*)&Vt[(j * 16 + lr) * 72 + 32 + kg * 8];
        accn[j] = __builtin_amdgcn_mfma_f32_16x16x32_bf16(ap0, c0, accn[j], 0, 0, 0);
        accn[j] = __builtin_amdgcn_mfma_f32_16x16x32_bf16(ap1, c1, accn[j], 0, 0, 0);
    }
    __syncthreads();

    u16* Op = O + ((size_t)b * L_ + (size_t)c * CHK) * E_ + h * 64;
    #pragma unroll
    for (int j = 0; j < 4; j++) {
        #pragma unroll
        for (int rr = 0; rr < 4; rr++) {
            int m = wm + kg * 4 + rr;
            int e = j * 16 + lr;
            Op[(size_t)m * E_ + e] = f2b(accn[j][rr] * invs[m]);
        }
    }
}

// ---------------------------------------------------------------------------
// 32x256 tile: X += A@Bt^T + bias (residual, fp32), then per-row epilogue.
// 256 threads, 4 waves (each 32 rows x 64 cols). BK=32, LDS dbuf pipeline.
// MODE 1: LayerNorm(row) -> Y bf16. MODE 2: final LN + pred head -> Out.
// ---------------------------------------------------------------------------
template <int MODE>
__device__ void dev_gres32(
    int task, const u16* __restrict__ A, const u16* __restrict__ Bt,
    const float* __restrict__ bias, float* __restrict__ X,
    const float* __restrict__ g, const float* __restrict__ bt,
    u16* __restrict__ Y, const float* __restrict__ W,
    const float* __restrict__ pb, float* __restrict__ Out,
    int Kd, char* sm)
{
    u16* AsB = (u16*)sm;             // [2][32*40]
    u16* BsB = (u16*)(sm + 5120);    // [2][256*40]
    int tid = threadIdx.x;
    int bm = task * 32;
    int wave = tid >> 6, lane = tid & 63;
    int wn = wave * 64;
    int lr = lane & 15, kg = lane >> 4;

    int sr = tid >> 2, ag = (tid & 3) * 8;   // sr: 0..63
    bool al = sr < 32;

    const u16* Ap = A + (size_t)(bm + sr) * Kd + ag;     // valid iff al
    const u16* Bp = Bt + (size_t)sr * Kd + ag;           // +64*q rows

    uint4 aR, bR[4];
    if (al) aR = *(const uint4*)(Ap);
    #pragma unroll
    for (int q = 0; q < 4; q++) bR[q] = *(const uint4*)(Bp + (size_t)(64 * q) * Kd);
    if (al) *(uint4*)&AsB[sr * 40 + ag] = aR;
    #pragma unroll
    for (int q = 0; q < 4; q++) *(uint4*)&BsB[(sr + 64 * q) * 40 + ag] = bR[q];

    f32x4 acc[2][4] = {};
    int NT = Kd >> 5;
    for (int t = 0; t < NT; ++t) {
        int cur = t & 1;
        __syncthreads();
        if (t + 1 < NT) {
            int k1 = (t + 1) << 5;
            if (al) aR = *(const uint4*)(Ap + k1);
            #pragma unroll
            for (int q = 0; q < 4; q++)
                bR[q] = *(const uint4*)(Bp + (size_t)(64 * q) * Kd + k1);
        }
        bf16x8 af[2], bg[4];
        #pragma unroll
        for (int i = 0; i < 2; i++)
            af[i] = *(const bf16x8*)&AsB[cur * 1280 + (i * 16 + lr) * 40 + kg * 8];
        #pragma unroll
        for (int j = 0; j < 4; j++)
            bg[j] = *(const bf16x8*)&BsB[cur * 10240 + (wn + j * 16 + lr) * 40 + kg * 8];
        #pragma unroll
        for (int i = 0; i < 2; i++)
            #pragma unroll
            for (int j = 0; j < 4; j++)
                acc[i][j] = __builtin_amdgcn_mfma_f32_16x16x32_bf16(
                    af[i], bg[j], acc[i][j], 0, 0, 0);
        if (t + 1 < NT) {
            if (al) *(uint4*)&AsB[(cur ^ 1) * 1280 + sr * 40 + ag] = aR;
            #pragma unroll
            for (int q = 0; q < 4; q++)
                *(uint4*)&BsB[(cur ^ 1) * 10240 + (sr + 64 * q) * 40 + ag] = bR[q];
        }
    }
    __syncthreads();   // LDS reads done; reuse as fp32 row buffer

    float* Xs = (float*)sm;    // [32][260]
    #pragma unroll
    for (int i = 0; i < 2; i++) {
        #pragma unroll
        for (int j = 0; j < 4; j++) {
            int col = wn + j * 16 + lr;
            float bc = bias[col];
            #pragma unroll
            for (int rr = 0; rr < 4; rr++) {
                int row = i * 16 + kg * 4 + rr;
                float v = acc[i][j][rr] + bc + X[(size_t)(bm + row) * 256 + col];
                Xs[row * 260 + col] = v;
            }
        }
    }
    __syncthreads();

    int e0 = lane * 4;
    #pragma unroll
    for (int rq = 0; rq < 8; rq++) {
        int row = wave * 8 + rq;
        float4 v = *(const float4*)&Xs[row * 260 + e0];
        if (MODE == 1) {
            *(float4*)(X + (size_t)(bm + row) * 256 + e0) = v;
            float s = v.x + v.y + v.z + v.w;
            #pragma unroll
            for (int o = 32; o; o >>= 1) s += __shfl_xor(s, o, 64);
            float mean = s * (1.f / E_);
            float dx = v.x - mean, dy = v.y - mean, dz = v.z - mean, dw = v.w - mean;
            float q = dx * dx + dy * dy + dz * dz + dw * dw;
            #pragma unroll
            for (int o = 32; o; o >>= 1) q += __shfl_xor(q, o, 64);
            float inv = rsqrtf(q * (1.f / E_) + LN_EPS);
            float4 gv = *(const float4*)(g + e0);
            float4 bv = *(const float4*)(bt + e0);
            ushort4 u;
            u.x = f2b(dx * inv * gv.x + bv.x); u.y = f2b(dy * inv * gv.y + bv.y);
            u.z = f2b(dz * inv * gv.z + bv.z); u.w = f2b(dw * inv * gv.w + bv.w);
            *(ushort4*)(Y + (size_t)(bm + row) * 256 + e0) = u;
        } else {
            // final layer: LN(normf) + prediction head for state tokens only
            int gr = bm + row;
            int b = gr / L_, l = gr % L_;
            if (l % 3 == 1) {
                float s = v.x + v.y + v.z + v.w;
                #pragma unroll
                for (int o = 32; o; o >>= 1) s += __shfl_xor(s, o, 64);
                float mean = s * (1.f / E_);
                float dx = v.x - mean, dy = v.y - mean, dz = v.z - mean, dw = v.w - mean;
                float q = dx * dx + dy * dy + dz * dz + dw * dw;
                #pragma unroll
                for (int o = 32; o; o >>= 1) q += __shfl_xor(q, o, 64);
                float inv = rsqrtf(q * (1.f / E_) + LN_EPS);
                float4 gv = *(const float4*)(g + e0);
                float4 bv = *(const float4*)(bt + e0);
                float y0 = dx * inv * gv.x + bv.x;
                float y1 = dy * inv * gv.y + bv.y;
                float y2 = dz * inv * gv.z + bv.z;
                float y3 = dw * inv * gv.w + bv.w;
                int si = b * K_ + l / 3;
                #pragma unroll
                for (int na = 0; na < NA_; na++) {
                    float a = y0 * W[(e0 + 0) * NA_ + na] + y1 * W[(e0 + 1) * NA_ + na]
                            + y2 * W[(e0 + 2) * NA_ + na] + y3 * W[(e0 + 3) * NA_ + na];
                    #pragma unroll
                    for (int o = 32; o; o >>= 1) a += __shfl_xor(a, o, 64);
                    if (lane == 0) Out[(size_t)si * NA_ + na] = a + pb[na];
                }
            }
        }
    }
}

// ---------------------------------------------------------------------------
// Persistent megakernel: entire forward pass, software grid barriers.
// ---------------------------------------------------------------------------
__global__ __launch_bounds__(256) void mega(MP p) {
    __shared__ __align__(16) char sm[46848];
    int NB = gridDim.x;

    // Stage 0: weight transpose (1536 tasks) + embed/LN1 (768 tasks)
    for (int t = blockIdx.x; t < 2304; t += NB) {
        if (t < 1536) dev_transpose(t, p, sm);
        else dev_embed(t - 1536, p);
        __syncthreads();
    }
    gbar(p.bar);

    for (int i = 0; i < NL_; i++) {
        // QKV projection + fused phi on q,k
        for (int t = blockIdx.x; t < 144; t += NB) {
            dev_mgemm128<2>(t, 6, p.yb, p.qkvT + (size_t)i * 196608,
                            p.qkv_b + i * 768, p.qkvb, 768, 256, sm);
            __syncthreads();
        }
        gbar(p.bar);
        for (int t = blockIdx.x; t < 192; t += NB) {
            dev_chunk_sum(t, p.qkvb, p.S, p.Z, sm);
            __syncthreads();
        }
        gbar(p.bar);
        for (int t = blockIdx.x; t < 192; t += NB) {
            dev_chunk_out(t, p.qkvb, p.S, p.Z, p.att, sm);
            __syncthreads();
        }
        gbar(p.bar);
        // attn out-proj + residual + LN2
        for (int t = blockIdx.x; t < 96; t += NB) {
            dev_gres32<1>(t, p.att, p.outT + (size_t)i * 65536, p.out_b + i * E_,
                          p.x, p.n2g + i * E_, p.n2b + i * E_, p.yb,
                          nullptr, nullptr, nullptr, 256, sm);
            __syncthreads();
        }
        gbar(p.bar);
        // FFN1 + exact gelu
        for (int t = blockIdx.x; t < 192; t += NB) {
            dev_mgemm128<1>(t, 8, p.yb, p.f1T + (size_t)i * 262144,
                            p.f1b + i * FF_, p.h1, 1024, 256, sm);
            __syncthreads();
        }
        gbar(p.bar);
        // FFN2 + residual, then LN1(next layer) or final LN + pred head
        if (i == 0) {
            for (int t = blockIdx.x; t < 96; t += NB) {
                dev_gres32<1>(t, p.h1, p.f2T, p.ffn2b, p.x,
                              p.n1g + E_, p.n1b + E_, p.yb,
                              nullptr, nullptr, nullptr, 1024, sm);
                __syncthreads();
            }
            gbar(p.bar);
        } else {
            for (int t = blockIdx.x; t < 96; t += NB) {
                dev_gres32<2>(t, p.h1, p.f2T + (size_t)i * 262144, p.ffn2b + i * E_,
                              p.x, p.nfg, p.nfb, nullptr,
                              p.pw, p.pb, p.out, 1024, sm);
                __syncthreads();
            }
        }
    }
}

// ---------------------------------------------------------------------------
extern "C" void kernel_launch(void* const* d_in, const int* in_sizes, int n_in,
                              void* d_out, int out_size, void* d_ws, size_t ws_size,
                              hipStream_t stream) {
    // workspace layout
    float* ws = (float*)d_ws;
    float* x    = ws;                        // 786432 f
    float* S    = x + 786432;                // 786432 f
    float* Z    = S + 786432;                // 12288 f
    u16*   yb   = (u16*)(Z + 12288);         // 786432 u16
    u16*   qkvb = yb + 786432;               // 2359296 u16
    u16*   att  = qkvb + 2359296;            // 786432
    u16*   h1   = att + 786432;              // 3145728
    u16*   qkvT = h1 + 3145728;              // 393216
    u16*   outT = qkvT + 393216;             // 131072
    u16*   f1T  = outT + 131072;             // 524288
    u16*   f2T  = f1T + 524288;              // 524288
    unsigned* bar = (unsigned*)(f2T + 524288);

    hipMemsetAsync(bar, 0, 256, stream);

    MP p;
    p.rtg      = (const float*)d_in[0];
    p.state    = (const float*)d_in[1];
    p.action   = (const float*)d_in[2];
    p.rtg_w    = (const float*)d_in[3];
    p.rtg_b    = (const float*)d_in[4];
    p.state_w  = (const float*)d_in[5];
    p.state_b  = (const float*)d_in[6];
    p.action_w = (const float*)d_in[7];
    p.action_b = (const float*)d_in[8];
    p.pos      = (const float*)d_in[9];
    p.n1g      = (const float*)d_in[10];
    p.n1b      = (const float*)d_in[11];
    p.qkv_w    = (const float*)d_in[12];
    p.qkv_b    = (const float*)d_in[13];
    p.out_w    = (const float*)d_in[14];
    p.out_b    = (const float*)d_in[15];
    p.n2g      = (const float*)d_in[16];
    p.n2b      = (const float*)d_in[17];
    p.f1w      = (const float*)d_in[18];
    p.f1b      = (const float*)d_in[19];
    p.f2w      = (const float*)d_in[20];
    p.ffn2b    = (const float*)d_in[21];
    p.nfg      = (const float*)d_in[22];
    p.nfb      = (const float*)d_in[23];
    p.pw       = (const float*)d_in[24];
    p.pb       = (const float*)d_in[25];
    p.x = x; p.S = S; p.Z = Z; p.out = (float*)d_out;
    p.yb = yb; p.qkvb = qkvb; p.att = att; p.h1 = h1;
    p.qkvT = qkvT; p.outT = outT; p.f1T = f1T; p.f2T = f2T;
    p.bar = bar;

    mega<<<dim3(NBLK), dim3(256), 0, stream>>>(p);
}

// Round 6
// 302.000 us; speedup vs baseline: 1.9004x; 1.6314x over previous
//
#include <hip/hip_runtime.h>
#include <hip/hip_bf16.h>
#include <math.h>

// Problem constants
#define B_  2
#define K_  512
#define SD_ 60
#define NA_ 5
#define E_  256
#define H_  4
#define D_  64
#define FF_ 1024
#define NL_ 2
#define L_  (3 * K_)          // 1536 tokens per batch
#define M_  (B_ * L_)         // 3072 rows total
#define EPS_F 1e-6f
#define LN_EPS 1e-5f
#define CHK 64
#define NC_ (L_ / CHK)        // 24 chunks per (b,h)

using bf16x8 = __attribute__((ext_vector_type(8))) short;
using f32x4  = __attribute__((ext_vector_type(4))) float;
typedef unsigned short u16;

__device__ inline u16 f2b(float v) {
    __hip_bfloat16 h = __float2bfloat16(v);
    return *(u16*)&h;
}
__device__ inline float b2f(u16 v) {
    __hip_bfloat16 h = *(__hip_bfloat16*)&v;
    return __bfloat162float(h);
}

// ---------------------------------------------------------------------------
// Init kernel: blocks 0..1535 = weight convert+transpose (32x32 tiles),
//              blocks 1536..2303 = embed + interleave + LN1(layer0)
// ---------------------------------------------------------------------------
__global__ __launch_bounds__(256) void init_kernel(
    const float* __restrict__ qkv_w, const float* __restrict__ out_w,
    const float* __restrict__ ffn1_w, const float* __restrict__ ffn2_w,
    u16* __restrict__ qkvT, u16* __restrict__ outT,
    u16* __restrict__ f1T, u16* __restrict__ f2T,
    const float* __restrict__ rtg, const float* __restrict__ state,
    const float* __restrict__ action,
    const float* __restrict__ rtg_w, const float* __restrict__ rtg_b,
    const float* __restrict__ state_w, const float* __restrict__ state_b,
    const float* __restrict__ action_w, const float* __restrict__ action_b,
    const float* __restrict__ pos,
    const float* __restrict__ g, const float* __restrict__ bta,
    float* __restrict__ X, u16* __restrict__ Y)
{
    __shared__ u16 T[32][33];
    if (blockIdx.x < 1536) {
        int tb = blockIdx.x;
        int layer = tb / 768;
        int r = tb % 768;
        const float* src; u16* dst; int K, N, tidx;
        if (r < 192)      { src = qkv_w  + layer * 196608; dst = qkvT + layer * 196608; K = 256;  N = 768;  tidx = r; }
        else if (r < 256) { src = out_w  + layer * 65536;  dst = outT + layer * 65536;  K = 256;  N = 256;  tidx = r - 192; }
        else if (r < 512) { src = ffn1_w + layer * 262144; dst = f1T  + layer * 262144; K = 256;  N = 1024; tidx = r - 256; }
        else              { src = ffn2_w + layer * 262144; dst = f2T  + layer * 262144; K = 1024; N = 256;  tidx = r - 512; }
        int tilesN = N >> 5;
        int k0 = (tidx / tilesN) << 5;
        int n0 = (tidx % tilesN) << 5;
        int c = threadIdx.x & 31, r0 = threadIdx.x >> 5;
        for (int rr = r0; rr < 32; rr += 8)
            T[rr][c] = f2b(src[(size_t)(k0 + rr) * N + n0 + c]);
        __syncthreads();
        for (int rr = r0; rr < 32; rr += 8)
            dst[(size_t)(n0 + rr) * K + k0 + c] = T[c][rr];
        return;
    }
    // embed + LN1(layer0)
    int tok = (blockIdx.x - 1536) * 4 + (threadIdx.x >> 6);
    int lane = threadIdx.x & 63;
    int b = tok / L_, l = tok % L_;
    int j = l % 3, t = l / 3;
    int e0 = lane * 4;
    float4 val = *(const float4*)(pos + t * E_ + e0);
    if (j == 0) {
        float rv = rtg[b * K_ + t];
        float4 w = *(const float4*)(rtg_w + e0);
        float4 bb = *(const float4*)(rtg_b + e0);
        val.x += rv * w.x + bb.x; val.y += rv * w.y + bb.y;
        val.z += rv * w.z + bb.z; val.w += rv * w.w + bb.w;
    } else if (j == 1) {
        float4 a = *(const float4*)(state_b + e0);
        const float* srow = state + ((size_t)b * K_ + t) * SD_;
        for (int i = 0; i < SD_; i++) {
            float s = srow[i];
            float4 w = *(const float4*)(state_w + (size_t)i * E_ + e0);
            a.x += s * w.x; a.y += s * w.y; a.z += s * w.z; a.w += s * w.w;
        }
        val.x += a.x; val.y += a.y; val.z += a.z; val.w += a.w;
    } else {
        float4 a = *(const float4*)(action_b + e0);
        const float* arow = action + ((size_t)b * K_ + t) * NA_;
        #pragma unroll
        for (int i = 0; i < NA_; i++) {
            float s = arow[i];
            float4 w = *(const float4*)(action_w + (size_t)i * E_ + e0);
            a.x += s * w.x; a.y += s * w.y; a.z += s * w.z; a.w += s * w.w;
        }
        val.x += a.x; val.y += a.y; val.z += a.z; val.w += a.w;
    }
    *(float4*)(X + (size_t)tok * E_ + e0) = val;
    float s = val.x + val.y + val.z + val.w;
    #pragma unroll
    for (int o = 32; o; o >>= 1) s += __shfl_xor(s, o, 64);
    float mean = s * (1.f / E_);
    float dx = val.x - mean, dy = val.y - mean, dz = val.z - mean, dw = val.w - mean;
    float q = dx * dx + dy * dy + dz * dz + dw * dw;
    #pragma unroll
    for (int o = 32; o; o >>= 1) q += __shfl_xor(q, o, 64);
    float inv = rsqrtf(q * (1.f / E_) + LN_EPS);
    float4 gv = *(const float4*)(g + e0);
    float4 bv = *(const float4*)(bta + e0);
    ushort4 u;
    u.x = f2b(dx * inv * gv.x + bv.x); u.y = f2b(dy * inv * gv.y + bv.y);
    u.z = f2b(dz * inv * gv.z + bv.z); u.w = f2b(dw * inv * gv.w + bv.w);
    *(ushort4*)(Y + (size_t)tok * E_ + e0) = u;
}

// ---------------------------------------------------------------------------
// MFMA bf16 GEMM: C[M,N] = epi(A[M,K]bf16 @ Bt[N,K]bf16^T + bias), bf16 out
// 128x128 tile, 256 threads = 4 waves (2x2 of 64x64), BK=32, LDS dbuf pipeline
// EPI: 1 exact gelu, 2 phi (relu+eps) on cols < 512 (QKV: q,k only)
// ---------------------------------------------------------------------------
template <int EPI>
__global__ __launch_bounds__(256) void mgemm(
    const u16* __restrict__ A, const u16* __restrict__ Bt,
    const float* __restrict__ bias,
    u16* __restrict__ C, int M, int N, int Kd)
{
    __shared__ __align__(16) u16 As[2][128 * 40];
    __shared__ __align__(16) u16 Bs[2][128 * 40];
    int tid = threadIdx.x;
    int bm = blockIdx.y * 128, bn = blockIdx.x * 128;
    int wave = tid >> 6, lane = tid & 63;
    int wm = (wave >> 1) * 64, wn = (wave & 1) * 64;
    int lr = lane & 15, kg = lane >> 4;

    int r0 = tid >> 2, g0 = (tid & 3) * 8;
    int r1 = r0 + 64;

    const u16* Ap0 = A + (size_t)(bm + r0) * Kd + g0;
    const u16* Ap1 = A + (size_t)(bm + r1) * Kd + g0;
    const u16* Bp0 = Bt + (size_t)(bn + r0) * Kd + g0;
    const u16* Bp1 = Bt + (size_t)(bn + r1) * Kd + g0;

    // prologue: stage tile 0 into buffer 0
    uint4 a0 = *(const uint4*)(Ap0);
    uint4 a1 = *(const uint4*)(Ap1);
    uint4 b0 = *(const uint4*)(Bp0);
    uint4 b1 = *(const uint4*)(Bp1);
    *(uint4*)&As[0][r0 * 40 + g0] = a0;
    *(uint4*)&As[0][r1 * 40 + g0] = a1;
    *(uint4*)&Bs[0][r0 * 40 + g0] = b0;
    *(uint4*)&Bs[0][r1 * 40 + g0] = b1;

    f32x4 acc[4][4] = {};
    int NT = Kd >> 5;
    for (int t = 0; t < NT; ++t) {
        int cur = t & 1;
        __syncthreads();
        if (t + 1 < NT) {                        // issue next tile's loads early
            int k1 = (t + 1) << 5;
            a0 = *(const uint4*)(Ap0 + k1);
            a1 = *(const uint4*)(Ap1 + k1);
            b0 = *(const uint4*)(Bp0 + k1);
            b1 = *(const uint4*)(Bp1 + k1);
        }
        bf16x8 af[4], bg[4];
        #pragma unroll
        for (int i = 0; i < 4; i++)
            af[i] = *(const bf16x8*)&As[cur][(wm + i * 16 + lr) * 40 + kg * 8];
        #pragma unroll
        for (int j = 0; j < 4; j++)
            bg[j] = *(const bf16x8*)&Bs[cur][(wn + j * 16 + lr) * 40 + kg * 8];
        #pragma unroll
        for (int i = 0; i < 4; i++)
            #pragma unroll
            for (int j = 0; j < 4; j++)
                acc[i][j] = __builtin_amdgcn_mfma_f32_16x16x32_bf16(
                    af[i], bg[j], acc[i][j], 0, 0, 0);
        if (t + 1 < NT) {                        // write next tile into other buf
            *(uint4*)&As[cur ^ 1][r0 * 40 + g0] = a0;
            *(uint4*)&As[cur ^ 1][r1 * 40 + g0] = a1;
            *(uint4*)&Bs[cur ^ 1][r0 * 40 + g0] = b0;
            *(uint4*)&Bs[cur ^ 1][r1 * 40 + g0] = b1;
        }
    }

    #pragma unroll
    for (int i = 0; i < 4; i++) {
        #pragma unroll
        for (int j = 0; j < 4; j++) {
            int col = bn + wn + j * 16 + lr;
            float bc = bias[col];
            #pragma unroll
            for (int r = 0; r < 4; r++) {
                int row = bm + wm + i * 16 + kg * 4 + r;
                float v = acc[i][j][r] + bc;
                if (EPI == 1) v = 0.5f * v * (1.0f + erff(v * 0.70710678118654752f));
                if (EPI == 2) { if (col < 512) v = fmaxf(v, 0.f) + EPS_F; }
                C[(size_t)row * N + col] = f2b(v);
            }
        }
    }
}

// ---------------------------------------------------------------------------
// Fused GEMM + residual + row epilogue. Tile = 64 rows x 256 cols (full
// width), 512 threads = 8 waves (2 wave-rows x 4 wave-cols of 32x64).
// BK=32, LDS dbuf pipeline; epilogue runs in two 32-row halves on LDS.
// MODE 1: X += A@Bt^T+bias; LN(X row) -> Y bf16.
// MODE 2: same GEMM+residual; final LN + prediction head (state rows only).
// ---------------------------------------------------------------------------
template <int MODE>
__global__ __launch_bounds__(512) void gfuse64(
    const u16* __restrict__ A, const u16* __restrict__ Bt,
    const float* __restrict__ bias, float* __restrict__ X,
    const float* __restrict__ g, const float* __restrict__ bt,
    u16* __restrict__ Y, const float* __restrict__ W,
    const float* __restrict__ pb, float* __restrict__ Out, int Kd)
{
    __shared__ __align__(16) char smem[51200];
    u16* As = (u16*)smem;              // [2][64*40]
    u16* Bs = (u16*)(smem + 10240);    // [2][256*40]
    int tid = threadIdx.x;
    int bm = blockIdx.x * 64;
    int wave = tid >> 6, lane = tid & 63;
    int wr = wave >> 2, wc = wave & 3;
    int lr = lane & 15, kg = lane >> 4;

    int arow = tid >> 2, aq = (tid & 3) * 8;   // A-stage: threads 0..255
    int brow = tid >> 1, bq = (tid & 1) * 16;  // B-stage: all 512 threads

    const u16* Ap = A + (size_t)(bm + arow) * Kd + aq;
    const u16* Bp = Bt + (size_t)brow * Kd + bq;

    uint4 a0; uint4 b0, b1;
    if (tid < 256) a0 = *(const uint4*)(Ap);
    b0 = *(const uint4*)(Bp);
    b1 = *(const uint4*)(Bp + 8);
    if (tid < 256) *(uint4*)&As[arow * 40 + aq] = a0;
    *(uint4*)&Bs[brow * 40 + bq] = b0;
    *(uint4*)&Bs[brow * 40 + bq + 8] = b1;

    f32x4 acc[2][4] = {};
    int NT = Kd >> 5;
    for (int t = 0; t < NT; ++t) {
        int cur = t & 1;
        __syncthreads();
        if (t + 1 < NT) {
            int k1 = (t + 1) << 5;
            if (tid < 256) a0 = *(const uint4*)(Ap + k1);
            b0 = *(const uint4*)(Bp + k1);
            b1 = *(const uint4*)(Bp + k1 + 8);
        }
        bf16x8 af[2], bg[4];
        #pragma unroll
        for (int i = 0; i < 2; i++)
            af[i] = *(const bf16x8*)&As[cur * 2560 + (wr * 32 + i * 16 + lr) * 40 + kg * 8];
        #pragma unroll
        for (int j = 0; j < 4; j++)
            bg[j] = *(const bf16x8*)&Bs[cur * 10240 + (wc * 64 + j * 16 + lr) * 40 + kg * 8];
        #pragma unroll
        for (int i = 0; i < 2; i++)
            #pragma unroll
            for (int j = 0; j < 4; j++)
                acc[i][j] = __builtin_amdgcn_mfma_f32_16x16x32_bf16(
                    af[i], bg[j], acc[i][j], 0, 0, 0);
        if (t + 1 < NT) {
            if (tid < 256) *(uint4*)&As[(cur ^ 1) * 2560 + arow * 40 + aq] = a0;
            *(uint4*)&Bs[(cur ^ 1) * 10240 + brow * 40 + bq] = b0;
            *(uint4*)&Bs[(cur ^ 1) * 10240 + brow * 40 + bq + 8] = b1;
        }
    }
    __syncthreads();   // all LDS reads done; reuse as fp32 row buffer

    float* Xs = (float*)smem;   // [32][260] = 33.3 KB <= 51.2 KB
    int e0 = lane * 4;
    #pragma unroll
    for (int h = 0; h < 2; ++h) {
        if (wr == h) {
            #pragma unroll
            for (int j = 0; j < 4; j++) {
                int col = wc * 64 + j * 16 + lr;
                float bc = bias[col];
                #pragma unroll
                for (int i = 0; i < 2; i++) {
                    #pragma unroll
                    for (int rr = 0; rr < 4; rr++) {
                        int r32 = i * 16 + kg * 4 + rr;
                        float v = acc[i][j][rr] + bc
                                + X[(size_t)(bm + 32 * h + r32) * 256 + col];
                        Xs[r32 * 260 + col] = v;
                    }
                }
            }
        }
        __syncthreads();
        // per-row epilogue: 8 waves x 4 rows = 32 rows
        #pragma unroll
        for (int q = 0; q < 4; q++) {
            int r32 = wave * 4 + q;
            int gr = bm + 32 * h + r32;
            float4 v = *(const float4*)&Xs[r32 * 260 + e0];
            if (MODE == 1) {
                *(float4*)(X + (size_t)gr * 256 + e0) = v;   // residual out
                float s = v.x + v.y + v.z + v.w;
                #pragma unroll
                for (int o = 32; o; o >>= 1) s += __shfl_xor(s, o, 64);
                float mean = s * (1.f / E_);
                float dx = v.x - mean, dy = v.y - mean, dz = v.z - mean, dw = v.w - mean;
                float qq = dx * dx + dy * dy + dz * dz + dw * dw;
                #pragma unroll
                for (int o = 32; o; o >>= 1) qq += __shfl_xor(qq, o, 64);
                float inv = rsqrtf(qq * (1.f / E_) + LN_EPS);
                float4 gv = *(const float4*)(g + e0);
                float4 bv = *(const float4*)(bt + e0);
                ushort4 u;
                u.x = f2b(dx * inv * gv.x + bv.x); u.y = f2b(dy * inv * gv.y + bv.y);
                u.z = f2b(dz * inv * gv.z + bv.z); u.w = f2b(dw * inv * gv.w + bv.w);
                *(ushort4*)(Y + (size_t)gr * 256 + e0) = u;
            } else {
                int b = gr / L_, l = gr % L_;
                if (l % 3 == 1) {
                    float s = v.x + v.y + v.z + v.w;
                    #pragma unroll
                    for (int o = 32; o; o >>= 1) s += __shfl_xor(s, o, 64);
                    float mean = s * (1.f / E_);
                    float dx = v.x - mean, dy = v.y - mean, dz = v.z - mean, dw = v.w - mean;
                    float qq = dx * dx + dy * dy + dz * dz + dw * dw;
                    #pragma unroll
                    for (int o = 32; o; o >>= 1) qq += __shfl_xor(qq, o, 64);
                    float inv = rsqrtf(qq * (1.f / E_) + LN_EPS);
                    float4 gv = *(const float4*)(g + e0);
                    float4 bv = *(const float4*)(bt + e0);
                    float y0 = dx * inv * gv.x + bv.x;
                    float y1 = dy * inv * gv.y + bv.y;
                    float y2 = dz * inv * gv.z + bv.z;
                    float y3 = dw * inv * gv.w + bv.w;
                    int si = b * K_ + l / 3;
                    #pragma unroll
                    for (int na = 0; na < NA_; na++) {
                        float a = y0 * W[(e0 + 0) * NA_ + na] + y1 * W[(e0 + 1) * NA_ + na]
                                + y2 * W[(e0 + 2) * NA_ + na] + y3 * W[(e0 + 3) * NA_ + na];
                        #pragma unroll
                        for (int o = 32; o; o >>= 1) a += __shfl_xor(a, o, 64);
                        if (lane == 0) Out[(size_t)si * NA_ + na] = a + pb[na];
                    }
                }
            }
        }
        __syncthreads();
    }
}

// ---------------------------------------------------------------------------
// Chunked linear attention; qkvb already holds phi(q)|phi(k)|v  (bf16)
// Pass A: per-chunk S[d][e] = sum_t k[t][d] v[t][e], z[d] = sum_t k[t][d]
// ---------------------------------------------------------------------------
__global__ __launch_bounds__(256) void chunk_sum_kernel(
    const u16* __restrict__ QKV, float* __restrict__ S, float* __restrict__ Z)
{
    int blk = blockIdx.x;                  // (b*H+h)*NC + c
    int c = blk % NC_;
    int bh = blk / NC_;
    int h = bh % H_;
    int b = bh / H_;
    __shared__ __align__(16) u16 Kt[64 * 72];   // [d][t]
    __shared__ __align__(16) u16 Vt[64 * 72];   // [e][t]
    int tid = threadIdx.x;
    const size_t base = ((size_t)b * L_ + (size_t)c * CHK) * 768 + h * 64;
    for (int i = tid; i < 1024; i += 256) {
        int t = i >> 4, d4 = (i & 15) << 2;
        ushort4 k = *(const ushort4*)(QKV + base + (size_t)t * 768 + 256 + d4);
        ushort4 v = *(const ushort4*)(QKV + base + (size_t)t * 768 + 512 + d4);
        Kt[(d4 + 0) * 72 + t] = k.x;
        Kt[(d4 + 1) * 72 + t] = k.y;
        Kt[(d4 + 2) * 72 + t] = k.z;
        Kt[(d4 + 3) * 72 + t] = k.w;
        Vt[(d4 + 0) * 72 + t] = v.x;
        Vt[(d4 + 1) * 72 + t] = v.y;
        Vt[(d4 + 2) * 72 + t] = v.z;
        Vt[(d4 + 3) * 72 + t] = v.w;
    }
    __syncthreads();
    int wave = tid >> 6, lane = tid & 63;
    int lr = lane & 15, kg = lane >> 4;
    int wm = wave * 16;
    bf16x8 a0 = *(const bf16x8*)&Kt[(wm + lr) * 72 + kg * 8];
    bf16x8 a1 = *(const bf16x8*)&Kt[(wm + lr) * 72 + 32 + kg * 8];
    f32x4 acc[4] = {};
    #pragma unroll
    for (int j = 0; j < 4; j++) {
        bf16x8 b0 = *(const bf16x8*)&Vt[(j * 16 + lr) * 72 + kg * 8];
        bf16x8 b1 = *(const bf16x8*)&Vt[(j * 16 + lr) * 72 + 32 + kg * 8];
        acc[j] = __builtin_amdgcn_mfma_f32_16x16x32_bf16(a0, b0, acc[j], 0, 0, 0);
        acc[j] = __builtin_amdgcn_mfma_f32_16x16x32_bf16(a1, b1, acc[j], 0, 0, 0);
    }
    if (tid < 64) {
        float z = 0.f;
        #pragma unroll 8
        for (int t = 0; t < 64; t++) z += b2f(Kt[tid * 72 + t]);
        Z[(size_t)blk * 64 + tid] = z;
    }
    float* Sp = S + (size_t)blk * 4096;
    #pragma unroll
    for (int j = 0; j < 4; j++) {
        #pragma unroll
        for (int rr = 0; rr < 4; rr++) {
            int d = wm + kg * 4 + rr;
            int e = j * 16 + lr;
            Sp[d * 64 + e] = acc[j][rr];
        }
    }
}

// ---------------------------------------------------------------------------
// Pass B (fused exclusive prefix):
// o = (Q@KVstate + tril(Q@K^T)@V) / max(Q.kz + rowsum, 1e-6)
// ---------------------------------------------------------------------------
__global__ __launch_bounds__(256) void chunk_out_kernel(
    const u16* __restrict__ QKV, const float* __restrict__ S,
    const float* __restrict__ Z, u16* __restrict__ O)
{
    int blk = blockIdx.x;
    int c = blk % NC_;
    int bh = blk / NC_;
    int h = bh % H_;
    int b = bh / H_;
    __shared__ __align__(16) u16 Qb[64 * 72];    // [t][d]
    __shared__ __align__(16) u16 Kb[64 * 72];    // [t][d]
    __shared__ __align__(16) u16 Vt[64 * 72];    // [e][t]
    __shared__ __align__(16) u16 KVt[64 * 72];   // [e][d]
    __shared__ __align__(16) u16 Ps[64 * 72];    // [t][s]
    __shared__ float kzs[64];
    __shared__ float rows[64];
    __shared__ float invs[64];
    int tid = threadIdx.x;
    const size_t base = ((size_t)b * L_ + (size_t)c * CHK) * 768 + h * 64;
    const float* Sbh = S + (size_t)bh * NC_ * 4096;
    for (int i = tid; i < 1024; i += 256) {
        int t = i >> 4, d4 = (i & 15) << 2;
        ushort4 q = *(const ushort4*)(QKV + base + (size_t)t * 768 + d4);
        ushort4 k = *(const ushort4*)(QKV + base + (size_t)t * 768 + 256 + d4);
        ushort4 v = *(const ushort4*)(QKV + base + (size_t)t * 768 + 512 + d4);
        *(ushort4*)&Qb[t * 72 + d4] = q;
        *(ushort4*)&Kb[t * 72 + d4] = k;
        Vt[(d4 + 0) * 72 + t] = v.x;
        Vt[(d4 + 1) * 72 + t] = v.y;
        Vt[(d4 + 2) * 72 + t] = v.z;
        Vt[(d4 + 3) * 72 + t] = v.w;
        int d = t, e4 = d4;
        float4 a = make_float4(0.f, 0.f, 0.f, 0.f);
        for (int cc = 0; cc < c; cc++) {
            float4 s4 = *(const float4*)(Sbh + (size_t)cc * 4096 + d * 64 + e4);
            a.x += s4.x; a.y += s4.y; a.z += s4.z; a.w += s4.w;
        }
        KVt[(e4 + 0) * 72 + d] = f2b(a.x);
        KVt[(e4 + 1) * 72 + d] = f2b(a.y);
        KVt[(e4 + 2) * 72 + d] = f2b(a.z);
        KVt[(e4 + 3) * 72 + d] = f2b(a.w);
    }
    if (tid < 64) {
        float z = 0.f;
        const float* Zbh = Z + (size_t)bh * NC_ * 64;
        for (int cc = 0; cc < c; cc++) z += Zbh[cc * 64 + tid];
        kzs[tid] = z;
    }
    __syncthreads();

    int wave = tid >> 6, lane = tid & 63;
    int lr = lane & 15, kg = lane >> 4;
    int wm = wave * 16;

    bf16x8 aq0 = *(const bf16x8*)&Qb[(wm + lr) * 72 + kg * 8];
    bf16x8 aq1 = *(const bf16x8*)&Qb[(wm + lr) * 72 + 32 + kg * 8];

    f32x4 accs[4] = {};
    #pragma unroll
    for (int j = 0; j < 4; j++) {
        bf16x8 b0 = *(const bf16x8*)&Kb[(j * 16 + lr) * 72 + kg * 8];
        bf16x8 b1 = *(const bf16x8*)&Kb[(j * 16 + lr) * 72 + 32 + kg * 8];
        accs[j] = __builtin_amdgcn_mfma_f32_16x16x32_bf16(aq0, b0, accs[j], 0, 0, 0);
        accs[j] = __builtin_amdgcn_mfma_f32_16x16x32_bf16(aq1, b1, accs[j], 0, 0, 0);
    }
    float rsum[4] = {0.f, 0.f, 0.f, 0.f};
    #pragma unroll
    for (int j = 0; j < 4; j++) {
        #pragma unroll
        for (int rr = 0; rr < 4; rr++) {
            int m = wm + kg * 4 + rr;
            int n = j * 16 + lr;
            float v = (n <= m) ? accs[j][rr] : 0.f;
            rsum[rr] += v;
            Ps[m * 72 + n] = f2b(v);
        }
    }
    #pragma unroll
    for (int rr = 0; rr < 4; rr++) {
        float s = rsum[rr];
        s += __shfl_xor(s, 1, 64);
        s += __shfl_xor(s, 2, 64);
        s += __shfl_xor(s, 4, 64);
        s += __shfl_xor(s, 8, 64);
        if (lr == 0) rows[wm + kg * 4 + rr] = s;
    }
    __syncthreads();

    if (tid < 64) {
        float den = rows[tid];
        float acc = 0.f;
        #pragma unroll 8
        for (int d = 0; d < 64; d++) acc += b2f(Qb[tid * 72 + d]) * kzs[d];
        invs[tid] = 1.f / fmaxf(den + acc, 1e-6f);
    }

    bf16x8 ap0 = *(const bf16x8*)&Ps[(wm + lr) * 72 + kg * 8];
    bf16x8 ap1 = *(const bf16x8*)&Ps[(wm + lr) * 72 + 32 + kg * 8];
    f32x4 accn[4] = {};
    #pragma unroll
    for (int j = 0; j < 4; j++) {
        bf16x8 b0 = *(const bf16x8*)&KVt[(j * 16 + lr) * 72 + kg * 8];
        bf16x8 b1 = *(const bf16x8*)&KVt[(j * 16 + lr) * 72 + 32 + kg * 8];
        accn[j] = __builtin_amdgcn_mfma_f32_16x16x32_bf16(aq0, b0, accn[j], 0, 0, 0);
        accn[j] = __builtin_amdgcn_mfma_f32_16x16x32_bf16(aq1, b1, accn[j], 0, 0, 0);
        bf16x8 c0 = *(const bf16x8*)&Vt[(j * 16 + lr) * 72 + kg * 8];
        bf16x8 c1 = *(const bf16x8*)&Vt[(j * 16 + lr) * 72 + 32 + kg * 8];
        accn[j] = __builtin_amdgcn_mfma_f32_16x16x32_bf16(ap0, c0, accn[j], 0, 0, 0);
        accn[j] = __builtin_amdgcn_mfma_f32_16x16x32_bf16(ap1, c1, accn[j], 0, 0, 0);
    }
    __syncthreads();

    u16* Op = O + ((size_t)b * L_ + (size_t)c * CHK) * E_ + h * 64;
    #pragma unroll
    for (int j = 0; j < 4; j++) {
        #pragma unroll
        for (int rr = 0; rr < 4; rr++) {
            int m = wm + kg * 4 + rr;
            int e = j * 16 + lr;
            Op[(size_t)m * E_ + e] = f2b(accn[j][rr] * invs[m]);
        }
    }
}

// ---------------------------------------------------------------------------
extern "C" void kernel_launch(void* const* d_in, const int* in_sizes, int n_in,
                              void* d_out, int out_size, void* d_ws, size_t ws_size,
                              hipStream_t stream) {
    const float* rtg      = (const float*)d_in[0];
    const float* state    = (const float*)d_in[1];
    const float* action   = (const float*)d_in[2];
    const float* rtg_w    = (const float*)d_in[3];
    const float* rtg_b    = (const float*)d_in[4];
    const float* state_w  = (const float*)d_in[5];
    const float* state_b  = (const float*)d_in[6];
    const float* action_w = (const float*)d_in[7];
    const float* action_b = (const float*)d_in[8];
    const float* pos_emb  = (const float*)d_in[9];
    const float* norm1_g  = (const float*)d_in[10];
    const float* norm1_b  = (const float*)d_in[11];
    const float* qkv_w    = (const float*)d_in[12];
    const float* qkv_b    = (const float*)d_in[13];
    const float* out_w    = (const float*)d_in[14];
    const float* out_b    = (const float*)d_in[15];
    const float* norm2_g  = (const float*)d_in[16];
    const float* norm2_b  = (const float*)d_in[17];
    const float* ffn1_w   = (const float*)d_in[18];
    const float* ffn1_b   = (const float*)d_in[19];
    const float* ffn2_w   = (const float*)d_in[20];
    const float* ffn2_b   = (const float*)d_in[21];
    const float* normf_g  = (const float*)d_in[22];
    const float* normf_b  = (const float*)d_in[23];
    const float* pred_w   = (const float*)d_in[24];
    const float* pred_b   = (const float*)d_in[25];
    float* out = (float*)d_out;

    // workspace layout
    float* ws = (float*)d_ws;
    float* x    = ws;                        // 786432 f
    float* S    = x + 786432;                // 786432 f
    float* Z    = S + 786432;                // 12288 f
    u16*   yb   = (u16*)(Z + 12288);         // 786432 u16
    u16*   qkvb = yb + 786432;               // 2359296 u16
    u16*   att  = qkvb + 2359296;            // 786432
    u16*   h1   = att + 786432;              // 3145728
    u16*   qkvT = h1 + 3145728;              // 393216
    u16*   outT = qkvT + 393216;             // 131072
    u16*   f1T  = outT + 131072;             // 524288
    u16*   f2T  = f1T + 524288;              // 524288

    init_kernel<<<2304, 256, 0, stream>>>(
        qkv_w, out_w, ffn1_w, ffn2_w, qkvT, outT, f1T, f2T,
        rtg, state, action, rtg_w, rtg_b, state_w, state_b,
        action_w, action_b, pos_emb, norm1_g, norm1_b, x, yb);

    for (int i = 0; i < NL_; i++) {
        // QKV projection with fused phi on q,k (cols < 512)
        mgemm<2><<<dim3(768 / 128, M_ / 128), 256, 0, stream>>>(
            yb, qkvT + (size_t)i * 196608, qkv_b + i * 768, qkvb,
            M_, 768, E_);
        chunk_sum_kernel<<<B_ * H_ * NC_, 256, 0, stream>>>(qkvb, S, Z);
        chunk_out_kernel<<<B_ * H_ * NC_, 256, 0, stream>>>(qkvb, S, Z, att);
        // attn out-proj + residual + LN2 (fused, 64-row full-width tiles)
        gfuse64<1><<<M_ / 64, 512, 0, stream>>>(
            att, outT + (size_t)i * 65536, out_b + i * E_, x,
            norm2_g + i * E_, norm2_b + i * E_, yb,
            nullptr, nullptr, nullptr, E_);
        // FFN1 + exact gelu
        mgemm<1><<<dim3(FF_ / 128, M_ / 128), 256, 0, stream>>>(
            yb, f1T + (size_t)i * 262144, ffn1_b + i * FF_, h1,
            M_, FF_, E_);
        // FFN2 + residual, then LN1(next) or final LN + pred head
        if (i == 0)
            gfuse64<1><<<M_ / 64, 512, 0, stream>>>(
                h1, f2T, ffn2_b, x,
                norm1_g + E_, norm1_b + E_, yb,
                nullptr, nullptr, nullptr, FF_);
        else
            gfuse64<2><<<M_ / 64, 512, 0, stream>>>(
                h1, f2T + (size_t)1 * 262144, ffn2_b + E_, x,
                normf_g, normf_b, nullptr,
                pred_w, pred_b, out, FF_);
    }
}